// Round 14
// baseline (176.299 us; speedup 1.0000x reference)
//
#include <hip/hip_runtime.h>
#include <math.h>

#define BATCH 32768

typedef unsigned int u32;

#if defined(__has_builtin)
#if __has_builtin(__builtin_amdgcn_permlane32_swap) && __has_builtin(__builtin_amdgcn_permlane16_swap)
#define USE_PERMLANE 1
#else
#define USE_PERMLANE 0
#endif
#if __has_builtin(__builtin_amdgcn_fdot2)
#define HAS_FDOT2 1
#else
#define HAS_FDOT2 0
#endif
#else
#define USE_PERMLANE 0
#define HAS_FDOT2 0
#endif

// ---------------------------------------------------------------------------
// Compile-time circuit derivation (lazy CNOT tracking over GF(2)).
// Physical index p (10 bits): lane = p>>4 (bits 9..4), reg t = p&15.
// One amp = one u32 = packed fp16 {re(lo), im(hi)}.
// Layer 0 folded into the embedding; layers 1..3 are generalized pair-mix
// gates. Each wave simulates TWO samples (a0/a1) sharing gate overhead.
// Cross-lane policy (rounds 9-13 ledger): VALU ops cost ~2cyc at the margin,
// DS ops are ~free -> ALL gate partner fetches via ds_swizzle/ds_bpermute.
// Round 14: batch-invariant tables (gate coeffs + gtab) precomputed by a
// tiny setup kernel into d_ws; main blocks just load them (removes libm
// startup serialization + per-block gtab VALU).
// ---------------------------------------------------------------------------
struct GateC { unsigned prt, sel; };
struct CircuitT { GateC g[4][10]; unsigned srow[10]; };

constexpr CircuitT make_circuit() {
  CircuitT C{};
  unsigned row[10], col[10];
  for (int b = 0; b < 10; ++b) { row[b] = 1u << b; col[b] = 1u << b; }
  for (int l = 0; l < 4; ++l) {
    for (int w = 0; w < 10; ++w) {
      C.g[l][w].prt = col[9 - w];
      C.g[l][w].sel = row[9 - w];
    }
    const int r = (l % 9) + 1;
    for (int w = 0; w < 10; ++w) {
      const int c = w, t = (w + r) % 10;
      const int bc = 9 - c, bt = 9 - t;
      row[bt] ^= row[bc];
      col[bc] ^= col[bt];
    }
  }
  for (int i = 0; i < 10; ++i) C.srow[i] = row[9 - i];
  return C;
}
constexpr CircuitT CIRC = make_circuit();

// Within-layer gate order (commuting gates; interleave DS bursts with REG work).
constexpr int ORD[4][10] = {
  {0,1,2,3,4,5,6,7,8,9},
  {0,6,1,7,2,8,3,4,9,5},
  {0,2,1,3,7,4,8,5,9,6},
  {0,3,1,2,4,5,6,7,8,9},
};

// ws layout (u32 units): [0..239] packed gate coeffs, [240..319] layer-0 raw,
// [320..1343] gtab (f32). Total 5376 bytes.
#define WS_WORDS 1344

// ---------------- cross-lane: all-DS for gate partner fetch ----------------
template<int M>
__device__ __forceinline__ u32 lshuf(u32 v, int lane, int bpa) {
  static_assert(M != 0, "mask must be nonzero");
  if constexpr ((M & 32) != 0) {
    return (u32)__builtin_amdgcn_ds_bpermute(bpa, (int)v);
  } else {
    return (u32)__builtin_amdgcn_ds_swizzle((int)v, 0x1F | (M << 10));
  }
}

// ---------------- float cross-lane (prenet/epilogue reductions) ----------------
template<int CTRL>
__device__ __forceinline__ float dppf(float v) {
  const int i = __float_as_int(v);
  return __int_as_float(__builtin_amdgcn_update_dpp(i, i, CTRL, 0xF, 0xF, false));
}
__device__ __forceinline__ float shflx(float v, int m) { return __shfl_xor(v, m, 64); }

__device__ __forceinline__ float wave_sum(float v, int lane) {
  v += dppf<0xB1>(v);
  v += dppf<0x4E>(v);
  v += dppf<0x141>(v);
  v += dppf<0x140>(v);
#if USE_PERMLANE
  { auto r = __builtin_amdgcn_permlane16_swap(__float_as_uint(v), __float_as_uint(v), false, false);
    v = __uint_as_float(r[0]) + __uint_as_float(r[1]); }
  { auto r = __builtin_amdgcn_permlane32_swap(__float_as_uint(v), __float_as_uint(v), false, false);
    v = __uint_as_float(r[0]) + __uint_as_float(r[1]); }
#else
  v += shflx(v, 16);
  v += shflx(v, 32);
#endif
  return v;
}

__device__ __forceinline__ float half_sum(float v) {
  v += dppf<0xB1>(v);
  v += dppf<0x4E>(v);
  v += dppf<0x141>(v);
  v += dppf<0x140>(v);
#if USE_PERMLANE
  { auto r = __builtin_amdgcn_permlane16_swap(__float_as_uint(v), __float_as_uint(v), false, false);
    v = __uint_as_float(r[0]) + __uint_as_float(r[1]); }
#else
  v += shflx(v, 16);
#endif
  return v;
}

__device__ __forceinline__ float xswapf(float v, int lane) {
#if USE_PERMLANE
  auto r = __builtin_amdgcn_permlane32_swap(__float_as_uint(v), __float_as_uint(v), false, false);
  return (lane & 32) ? __uint_as_float(r[0]) : __uint_as_float(r[1]);
#else
  return shflx(v, 32);
#endif
}

// ---------------- packed fp16 primitives ----------------
__device__ __forceinline__ u32 pk_mul_h(u32 a, u32 b) {
  u32 d; asm("v_pk_mul_f16 %0, %1, %2" : "=v"(d) : "v"(a), "v"(b)); return d;
}
__device__ __forceinline__ u32 pk_fma_h(u32 a, u32 b, u32 c) {
  u32 d; asm("v_pk_fma_f16 %0, %1, %2, %3" : "=v"(d) : "v"(a), "v"(b), "v"(c)); return d;
}
__device__ __forceinline__ u32 pk_fma_hsw(u32 a, u32 b, u32 c) {
  u32 d;
  asm("v_pk_fma_f16 %0, %1, %2, %3 op_sel:[1,0,0] op_sel_hi:[0,1,1]"
      : "=v"(d) : "v"(a), "v"(b), "v"(c));
  return d;
}
__device__ __forceinline__ u32 pk2(float lo, float hi) {
  auto h = __builtin_amdgcn_cvt_pkrtz(lo, hi);
  return __builtin_bit_cast(u32, h);
}
__device__ __forceinline__ u32 updh(u32 a, u32 q, const uint4 s) {
  u32 t = pk_mul_h(a, s.x);
  t = pk_fma_hsw(a, s.y, t);
  t = pk_fma_h(q, s.z, t);
  t = pk_fma_hsw(q, s.w, t);
  return t;
}

// ---------------- shared table computation (used by setup & fallback) ------
__device__ __forceinline__ void compute_gate_words(int g, const float* __restrict__ qw,
                                                   u32* __restrict__ dst /* base of table */) {
  const float phi = qw[g * 3 + 0];
  const float th  = qw[g * 3 + 1];
  const float om  = qw[g * 3 + 2];
  const float c = cosf(0.5f * th), s_ = sinf(0.5f * th);
  const float A  = c;
  const float Br = -cosf(phi) * s_, Bi = -sinf(phi) * s_;
  const float Cr =  cosf(om)  * s_, Ci =  sinf(om)  * s_;
  const float Dr =  cosf(phi + om) * c, Di = sinf(phi + om) * c;
  if (g < 10) {
    u32* q = dst + 240 + g * 8;
    q[0] = __float_as_uint(A);  q[1] = __float_as_uint(Br);
    q[2] = __float_as_uint(Bi); q[3] = __float_as_uint(Cr);
    q[4] = __float_as_uint(Ci); q[5] = __float_as_uint(Dr);
    q[6] = __float_as_uint(Di); q[7] = 0u;
  } else {
    u32* p = dst + (g - 10) * 8;
    p[0] = pk2(A, A);   p[1] = pk2(0.f, 0.f);
    p[2] = pk2(Br, Br); p[3] = pk2(-Bi, Bi);
    p[4] = pk2(Dr, Dr); p[5] = pk2(-Di, Di);
    p[6] = pk2(Cr, Cr); p[7] = pk2(-Ci, Ci);
  }
}

__device__ __forceinline__ float compute_gtab_entry(int idx, const float* __restrict__ Wpost) {
  const int t = idx >> 6;
  const int l6 = idx & 63;
  float g = 0.f;
#pragma unroll
  for (int i = 0; i < 10; ++i) {
    const int sl = (int)(CIRC.srow[i] >> 4);
    const int sr = (int)(CIRC.srow[i] & 15u);
    const int par = (__popc(l6 & sl) + __popc(t & sr)) & 1;
    const float wv = Wpost[i];
    g += par ? -wv : wv;
  }
  return g;
}

// ---------------- setup kernel: batch-invariant tables -> d_ws ----------------
__global__ void qnn_setup(const float* __restrict__ qw, const float* __restrict__ Wpost,
                          u32* __restrict__ ws) {
  const int tid = threadIdx.x;     // 64 threads
  if (tid < 40) compute_gate_words(tid, qw, ws);
  float* gt = (float*)(ws + 320);
#pragma unroll
  for (int k = 0; k < 16; ++k) {
    const int idx = k * 64 + tid;
    gt[idx] = compute_gtab_entry(idx, Wpost);
  }
}

// ---------------- gate on two states (shared overhead) ----------------
template<int L, int W>
__device__ __forceinline__ void gate2(u32 a0[16], u32 a1[16],
                                      const u32* __restrict__ Ush, int lane) {
  constexpr unsigned PRT = CIRC.g[L][W].prt;
  constexpr unsigned SEL = CIRC.g[L][W].sel;
  constexpr int PLm = (int)(PRT >> 4), PRm = (int)(PRT & 15u);
  constexpr int SLm = (int)(SEL >> 4), SRm = (int)(SEL & 15u);

  int hl = 0;
  if constexpr (SLm != 0) hl = __popc(lane & SLm) & 1;

  const u32* gb = Ush + (L * 10 + W - 10) * 8;
  const uint4 cA = *(const uint4*)(gb + (hl << 2));
  uint4 cB;
  if constexpr (SRm != 0) cB = *(const uint4*)(gb + ((hl ^ 1) << 2));
  else                    cB = cA;

  int bpa = 0;
  if constexpr ((PLm & 32) != 0) bpa = (lane ^ PLm) << 2;

  if constexpr (PLm == 0) {
    constexpr int LB = PRm & (-PRm);
#pragma unroll
    for (int t0 = 0; t0 < 16; ++t0) {
      if (t0 & LB) continue;
      const int t1 = t0 ^ PRm;
      const uint4 s0 = (__builtin_popcount((unsigned)(t0 & SRm)) & 1) ? cB : cA;
      const uint4 s1 = (__builtin_popcount((unsigned)(t1 & SRm)) & 1) ? cB : cA;
      const u32 x0 = a0[t0], x1 = a0[t1];
      a0[t0] = updh(x0, x1, s0);
      a0[t1] = updh(x1, x0, s1);
      const u32 y0 = a1[t0], y1 = a1[t1];
      a1[t0] = updh(y0, y1, s0);
      a1[t1] = updh(y1, y0, s1);
    }
  } else {
#pragma unroll
    for (int t = 0; t < 16; ++t) {
      const uint4 s = (__builtin_popcount((unsigned)(t & SRm)) & 1) ? cB : cA;
      const u32 q0 = lshuf<PLm>(a0[t ^ PRm], lane, bpa);
      const u32 q1 = lshuf<PLm>(a1[t ^ PRm], lane, bpa);
      a0[t] = updh(a0[t], q0, s);
      a1[t] = updh(a1[t], q1, s);
    }
  }
}

template<int L, int K>
__device__ __forceinline__ void layer2_from(u32 a0[16], u32 a1[16],
                                            const u32* __restrict__ Ush, int lane) {
  if constexpr (K < 10) {
    gate2<L, ORD[L][K]>(a0, a1, Ush, lane);
    layer2_from<L, K + 1>(a0, a1, Ush, lane);
  }
}

// ---------------- embedding with layer-0 fold -> packed state ----------------
__device__ __forceinline__ void build_state(u32 a[16], const float cw[10], const float sw[10],
                                            const u32* __restrict__ Ush, int lane) {
  float u0r[10], u0i[10], u1r[10], u1i[10];
#pragma unroll
  for (int w = 0; w < 10; ++w) {
    const u32* q = &Ush[240 + w * 8];
    const float A = __uint_as_float(q[0]), Br = __uint_as_float(q[1]);
    const float Bi = __uint_as_float(q[2]), Cr = __uint_as_float(q[3]);
    const float Ci = __uint_as_float(q[4]), Dr = __uint_as_float(q[5]);
    const float Di = __uint_as_float(q[6]);
    const float ch = cw[w], sh = sw[w];
    u0r[w] = fmaf(A, ch, Bi * sh);
    u0i[w] = -Br * sh;
    u1r[w] = fmaf(Cr, ch, Di * sh);
    u1i[w] = fmaf(Ci, ch, -Dr * sh);
  }

  float Lr, Li;
  {
    const int b0 = (lane >> 5) & 1;
    Lr = b0 ? u1r[0] : u0r[0];
    Li = b0 ? u1i[0] : u0i[0];
  }
#pragma unroll
  for (int w = 1; w < 6; ++w) {
    const int bb = (lane >> (5 - w)) & 1;
    const float arv = bb ? u1r[w] : u0r[w];
    const float aiv = bb ? u1i[w] : u0i[w];
    const float nr = fmaf(Lr, arv, -Li * aiv);
    const float ni = fmaf(Lr, aiv, Li * arv);
    Lr = nr; Li = ni;
  }

  float t4r[4], t4i[4], lsr[4], lsi[4];
#pragma unroll
  for (int aa = 0; aa < 2; ++aa) {
#pragma unroll
    for (int c2 = 0; c2 < 2; ++c2) {
      const int k = (aa << 1) | c2;
      const float ar6 = aa ? u1r[6] : u0r[6], ai6 = aa ? u1i[6] : u0i[6];
      const float ar7 = c2 ? u1r[7] : u0r[7], ai7 = c2 ? u1i[7] : u0i[7];
      t4r[k] = fmaf(ar6, ar7, -ai6 * ai7);
      t4i[k] = fmaf(ar6, ai7, ai6 * ar7);
      const float ar8 = aa ? u1r[8] : u0r[8], ai8 = aa ? u1i[8] : u0i[8];
      const float ar9 = c2 ? u1r[9] : u0r[9], ai9 = c2 ? u1i[9] : u0i[9];
      const float s4r = fmaf(ar8, ar9, -ai8 * ai9);
      const float s4i = fmaf(ar8, ai9, ai8 * ar9);
      lsr[k] = fmaf(s4r, Lr, -s4i * Li);
      lsi[k] = fmaf(s4r, Li, s4i * Lr);
    }
  }

#pragma unroll
  for (int t = 0; t < 16; ++t) {
    const int hi4 = t >> 2, lo4 = t & 3;
    const float re = fmaf(t4r[hi4], lsr[lo4], -t4i[hi4] * lsi[lo4]);
    const float im = fmaf(t4r[hi4], lsi[lo4],  t4i[hi4] * lsr[lo4]);
    a[t] = pk2(re, im);
  }
}

// ---------------- main kernel: one wave per TWO samples ----------------
template<bool FROMWS>
__global__ __launch_bounds__(256, 8) void qnn_kernel(
    const float* __restrict__ x, const float* __restrict__ Wpre,
    const float* __restrict__ bpre, const float* __restrict__ qw,
    const float* __restrict__ Wpost, const float* __restrict__ bpost,
    const u32* __restrict__ ws, float* __restrict__ out)
{
  __shared__ __align__(16) u32 Ush[320];
  __shared__ __align__(16) float gtab[16 * 64];

  const int tid = threadIdx.x;
  if constexpr (FROMWS) {
    if (tid < 80) ((uint4*)Ush)[tid] = ((const uint4*)ws)[tid];
    ((float4*)gtab)[tid] = ((const float4*)(ws + 320))[tid];
  } else {
    if (tid < 40) compute_gate_words(tid, qw, Ush);
#pragma unroll
    for (int k = 0; k < 4; ++k) {
      const int idx = tid * 4 + k;
      gtab[idx] = compute_gtab_entry(idx, Wpost);
    }
  }
  __syncthreads();

  const int lane = tid & 63;
  const int wid = tid >> 6;
  const int half = lane >> 5;
  const int hl5 = lane & 31;
  const int b0 = blockIdx.x * 8 + wid * 2;

  // ---- pre-net, half-wave: lanes 0-31 -> b0, lanes 32-63 -> b1 ----
  const float* xr = x + (size_t)(b0 + half) * 128;
  float xv[4];
#pragma unroll
  for (int k = 0; k < 4; ++k) xv[k] = xr[hl5 + 32 * k];

  float cw0[10], sw0[10], cw1[10], sw1[10];
#pragma unroll
  for (int w = 0; w < 10; ++w) {
    float p = 0.f;
#pragma unroll
    for (int k = 0; k < 4; ++k)
      p = fmaf(xv[k], Wpre[w * 128 + hl5 + 32 * k], p);
    p = half_sum(p);
    const float e = __expf(2.f * (p + bpre[w]));
    const float ang = 1.f - 2.f * __builtin_amdgcn_rcpf(e + 1.f);
    const float h = 0.5f * ang;
    const float c_own = __cosf(h);
    const float s_own = __sinf(h);
    const float c_oth = xswapf(c_own, lane);
    const float s_oth = xswapf(s_own, lane);
    cw0[w] = half ? c_oth : c_own;
    sw0[w] = half ? s_oth : s_own;
    cw1[w] = half ? c_own : c_oth;
    sw1[w] = half ? s_own : s_oth;
  }

  // ---- build both states (embedding + layer-0 fold) ----
  u32 a0[16], a1[16];
  build_state(a0, cw0, sw0, Ush, lane);
  build_state(a1, cw1, sw1, Ush, lane);

  // ---- layers 1..3, both samples, shared gate overhead ----
  layer2_from<1, 0>(a0, a1, Ush, lane);
  layer2_from<2, 0>(a0, a1, Ush, lane);
  layer2_from<3, 0>(a0, a1, Ush, lane);

  // ---- epilogue ----
  float acc0 = 0.f, acc1 = 0.f;
#pragma unroll
  for (int t = 0; t < 16; ++t) {
    const float g = gtab[t * 64 + lane];
#if HAS_FDOT2
    typedef _Float16 h2 __attribute__((ext_vector_type(2)));
    const h2 ah0 = __builtin_bit_cast(h2, a0[t]);
    const h2 ah1 = __builtin_bit_cast(h2, a1[t]);
    acc0 = fmaf(__builtin_amdgcn_fdot2(ah0, ah0, 0.f, false), g, acc0);
    acc1 = fmaf(__builtin_amdgcn_fdot2(ah1, ah1, 0.f, false), g, acc1);
#else
    union H2U { u32 u; _Float16 h[2]; } z0, z1;
    z0.u = a0[t]; z1.u = a1[t];
    const float r0 = (float)z0.h[0], i0 = (float)z0.h[1];
    const float r1 = (float)z1.h[0], i1 = (float)z1.h[1];
    acc0 = fmaf(fmaf(r0, r0, i0 * i0), g, acc0);
    acc1 = fmaf(fmaf(r1, r1, i1 * i1), g, acc1);
#endif
  }
  acc0 = wave_sum(acc0, lane);
  acc1 = wave_sum(acc1, lane);

  if (lane == 0) {
    const float bp = bpost[0];
    out[b0]     = __builtin_amdgcn_rcpf(1.f + __expf(-(acc0 + bp)));
    out[b0 + 1] = __builtin_amdgcn_rcpf(1.f + __expf(-(acc1 + bp)));
  }
}

extern "C" void kernel_launch(void* const* d_in, const int* in_sizes, int n_in,
                              void* d_out, int out_size, void* d_ws, size_t ws_size,
                              hipStream_t stream) {
  const float* x     = (const float*)d_in[0];
  const float* Wpre  = (const float*)d_in[1];
  const float* bpre  = (const float*)d_in[2];
  const float* qw    = (const float*)d_in[3];
  const float* Wpost = (const float*)d_in[4];
  const float* bpost = (const float*)d_in[5];
  float* out = (float*)d_out;
  u32* ws = (u32*)d_ws;

  (void)in_sizes; (void)n_in; (void)out_size;

  if (ws_size >= WS_WORDS * sizeof(u32)) {
    qnn_setup<<<1, 64, 0, stream>>>(qw, Wpost, ws);
    qnn_kernel<true><<<BATCH / 8, 256, 0, stream>>>(x, Wpre, bpre, qw, Wpost, bpost, ws, out);
  } else {
    qnn_kernel<false><<<BATCH / 8, 256, 0, stream>>>(x, Wpre, bpre, qw, Wpost, bpost, ws, out);
  }
}

// Round 15
// 155.312 us; speedup vs baseline: 1.1351x; 1.1351x over previous
//
#include <hip/hip_runtime.h>
#include <math.h>

#define BATCH 32768

typedef unsigned int u32;

#if defined(__has_builtin)
#if __has_builtin(__builtin_amdgcn_permlane32_swap) && __has_builtin(__builtin_amdgcn_permlane16_swap)
#define USE_PERMLANE 1
#else
#define USE_PERMLANE 0
#endif
#if __has_builtin(__builtin_amdgcn_fdot2)
#define HAS_FDOT2 1
#else
#define HAS_FDOT2 0
#endif
#else
#define USE_PERMLANE 0
#define HAS_FDOT2 0
#endif

// ---------------------------------------------------------------------------
// Compile-time circuit derivation (lazy CNOT tracking over GF(2)).
// Physical index p (10 bits): lane = p>>4 (bits 9..4), reg t = p&15.
// One amp = one u32 = packed fp16 {re(lo), im(hi)}.
// Layer 0 folded into the embedding; layers 1..3 are generalized pair-mix
// gates. Each wave simulates TWO samples (a0/a1) sharing gate overhead.
// Cross-lane policy (rounds 9-13 ledger): VALU ops cost ~2cyc at the margin,
// DS ops are ~free -> ALL gate partner fetches via ds_swizzle/ds_bpermute.
// Round 15: setup kernel precomputes batch-invariant tables into d_ws
// (round-14 idea) but with the round-13 register budget (256,4) — round 14's
// (256,8) forced VGPR=32 and spilled to scratch (135 MB writes/dispatch).
// ---------------------------------------------------------------------------
struct GateC { unsigned prt, sel; };
struct CircuitT { GateC g[4][10]; unsigned srow[10]; };

constexpr CircuitT make_circuit() {
  CircuitT C{};
  unsigned row[10], col[10];
  for (int b = 0; b < 10; ++b) { row[b] = 1u << b; col[b] = 1u << b; }
  for (int l = 0; l < 4; ++l) {
    for (int w = 0; w < 10; ++w) {
      C.g[l][w].prt = col[9 - w];
      C.g[l][w].sel = row[9 - w];
    }
    const int r = (l % 9) + 1;
    for (int w = 0; w < 10; ++w) {
      const int c = w, t = (w + r) % 10;
      const int bc = 9 - c, bt = 9 - t;
      row[bt] ^= row[bc];
      col[bc] ^= col[bt];
    }
  }
  for (int i = 0; i < 10; ++i) C.srow[i] = row[9 - i];
  return C;
}
constexpr CircuitT CIRC = make_circuit();

// Within-layer gate order (commuting gates; interleave DS bursts with REG work).
constexpr int ORD[4][10] = {
  {0,1,2,3,4,5,6,7,8,9},
  {0,6,1,7,2,8,3,4,9,5},
  {0,2,1,3,7,4,8,5,9,6},
  {0,3,1,2,4,5,6,7,8,9},
};

// ws layout (u32 units): [0..239] packed gate coeffs, [240..319] layer-0 raw,
// [320..1343] gtab (f32). Total 5376 bytes.
#define WS_WORDS 1344

// ---------------- cross-lane: all-DS for gate partner fetch ----------------
template<int M>
__device__ __forceinline__ u32 lshuf(u32 v, int lane, int bpa) {
  static_assert(M != 0, "mask must be nonzero");
  if constexpr ((M & 32) != 0) {
    return (u32)__builtin_amdgcn_ds_bpermute(bpa, (int)v);
  } else {
    return (u32)__builtin_amdgcn_ds_swizzle((int)v, 0x1F | (M << 10));
  }
}

// ---------------- float cross-lane (prenet/epilogue reductions) ----------------
template<int CTRL>
__device__ __forceinline__ float dppf(float v) {
  const int i = __float_as_int(v);
  return __int_as_float(__builtin_amdgcn_update_dpp(i, i, CTRL, 0xF, 0xF, false));
}
__device__ __forceinline__ float shflx(float v, int m) { return __shfl_xor(v, m, 64); }

__device__ __forceinline__ float wave_sum(float v, int lane) {
  v += dppf<0xB1>(v);
  v += dppf<0x4E>(v);
  v += dppf<0x141>(v);
  v += dppf<0x140>(v);
#if USE_PERMLANE
  { auto r = __builtin_amdgcn_permlane16_swap(__float_as_uint(v), __float_as_uint(v), false, false);
    v = __uint_as_float(r[0]) + __uint_as_float(r[1]); }
  { auto r = __builtin_amdgcn_permlane32_swap(__float_as_uint(v), __float_as_uint(v), false, false);
    v = __uint_as_float(r[0]) + __uint_as_float(r[1]); }
#else
  v += shflx(v, 16);
  v += shflx(v, 32);
#endif
  return v;
}

__device__ __forceinline__ float half_sum(float v) {
  v += dppf<0xB1>(v);
  v += dppf<0x4E>(v);
  v += dppf<0x141>(v);
  v += dppf<0x140>(v);
#if USE_PERMLANE
  { auto r = __builtin_amdgcn_permlane16_swap(__float_as_uint(v), __float_as_uint(v), false, false);
    v = __uint_as_float(r[0]) + __uint_as_float(r[1]); }
#else
  v += shflx(v, 16);
#endif
  return v;
}

__device__ __forceinline__ float xswapf(float v, int lane) {
#if USE_PERMLANE
  auto r = __builtin_amdgcn_permlane32_swap(__float_as_uint(v), __float_as_uint(v), false, false);
  return (lane & 32) ? __uint_as_float(r[0]) : __uint_as_float(r[1]);
#else
  return shflx(v, 32);
#endif
}

// ---------------- packed fp16 primitives ----------------
__device__ __forceinline__ u32 pk_mul_h(u32 a, u32 b) {
  u32 d; asm("v_pk_mul_f16 %0, %1, %2" : "=v"(d) : "v"(a), "v"(b)); return d;
}
__device__ __forceinline__ u32 pk_fma_h(u32 a, u32 b, u32 c) {
  u32 d; asm("v_pk_fma_f16 %0, %1, %2, %3" : "=v"(d) : "v"(a), "v"(b), "v"(c)); return d;
}
__device__ __forceinline__ u32 pk_fma_hsw(u32 a, u32 b, u32 c) {
  u32 d;
  asm("v_pk_fma_f16 %0, %1, %2, %3 op_sel:[1,0,0] op_sel_hi:[0,1,1]"
      : "=v"(d) : "v"(a), "v"(b), "v"(c));
  return d;
}
__device__ __forceinline__ u32 pk2(float lo, float hi) {
  auto h = __builtin_amdgcn_cvt_pkrtz(lo, hi);
  return __builtin_bit_cast(u32, h);
}
__device__ __forceinline__ u32 updh(u32 a, u32 q, const uint4 s) {
  u32 t = pk_mul_h(a, s.x);
  t = pk_fma_hsw(a, s.y, t);
  t = pk_fma_h(q, s.z, t);
  t = pk_fma_hsw(q, s.w, t);
  return t;
}

// ---------------- shared table computation (used by setup & fallback) ------
__device__ __forceinline__ void compute_gate_words(int g, const float* __restrict__ qw,
                                                   u32* __restrict__ dst /* base of table */) {
  const float phi = qw[g * 3 + 0];
  const float th  = qw[g * 3 + 1];
  const float om  = qw[g * 3 + 2];
  const float c = cosf(0.5f * th), s_ = sinf(0.5f * th);
  const float A  = c;
  const float Br = -cosf(phi) * s_, Bi = -sinf(phi) * s_;
  const float Cr =  cosf(om)  * s_, Ci =  sinf(om)  * s_;
  const float Dr =  cosf(phi + om) * c, Di = sinf(phi + om) * c;
  if (g < 10) {
    u32* q = dst + 240 + g * 8;
    q[0] = __float_as_uint(A);  q[1] = __float_as_uint(Br);
    q[2] = __float_as_uint(Bi); q[3] = __float_as_uint(Cr);
    q[4] = __float_as_uint(Ci); q[5] = __float_as_uint(Dr);
    q[6] = __float_as_uint(Di); q[7] = 0u;
  } else {
    u32* p = dst + (g - 10) * 8;
    p[0] = pk2(A, A);   p[1] = pk2(0.f, 0.f);
    p[2] = pk2(Br, Br); p[3] = pk2(-Bi, Bi);
    p[4] = pk2(Dr, Dr); p[5] = pk2(-Di, Di);
    p[6] = pk2(Cr, Cr); p[7] = pk2(-Ci, Ci);
  }
}

__device__ __forceinline__ float compute_gtab_entry(int idx, const float* __restrict__ Wpost) {
  const int t = idx >> 6;
  const int l6 = idx & 63;
  float g = 0.f;
#pragma unroll
  for (int i = 0; i < 10; ++i) {
    const int sl = (int)(CIRC.srow[i] >> 4);
    const int sr = (int)(CIRC.srow[i] & 15u);
    const int par = (__popc(l6 & sl) + __popc(t & sr)) & 1;
    const float wv = Wpost[i];
    g += par ? -wv : wv;
  }
  return g;
}

// ---------------- setup kernel: batch-invariant tables -> d_ws ----------------
__global__ void qnn_setup(const float* __restrict__ qw, const float* __restrict__ Wpost,
                          u32* __restrict__ ws) {
  const int tid = threadIdx.x;     // 64 threads
  if (tid < 40) compute_gate_words(tid, qw, ws);
  float* gt = (float*)(ws + 320);
#pragma unroll
  for (int k = 0; k < 16; ++k) {
    const int idx = k * 64 + tid;
    gt[idx] = compute_gtab_entry(idx, Wpost);
  }
}

// ---------------- gate on two states (shared overhead) ----------------
template<int L, int W>
__device__ __forceinline__ void gate2(u32 a0[16], u32 a1[16],
                                      const u32* __restrict__ Ush, int lane) {
  constexpr unsigned PRT = CIRC.g[L][W].prt;
  constexpr unsigned SEL = CIRC.g[L][W].sel;
  constexpr int PLm = (int)(PRT >> 4), PRm = (int)(PRT & 15u);
  constexpr int SLm = (int)(SEL >> 4), SRm = (int)(SEL & 15u);

  int hl = 0;
  if constexpr (SLm != 0) hl = __popc(lane & SLm) & 1;

  const u32* gb = Ush + (L * 10 + W - 10) * 8;
  const uint4 cA = *(const uint4*)(gb + (hl << 2));
  uint4 cB;
  if constexpr (SRm != 0) cB = *(const uint4*)(gb + ((hl ^ 1) << 2));
  else                    cB = cA;

  int bpa = 0;
  if constexpr ((PLm & 32) != 0) bpa = (lane ^ PLm) << 2;

  if constexpr (PLm == 0) {
    constexpr int LB = PRm & (-PRm);
#pragma unroll
    for (int t0 = 0; t0 < 16; ++t0) {
      if (t0 & LB) continue;
      const int t1 = t0 ^ PRm;
      const uint4 s0 = (__builtin_popcount((unsigned)(t0 & SRm)) & 1) ? cB : cA;
      const uint4 s1 = (__builtin_popcount((unsigned)(t1 & SRm)) & 1) ? cB : cA;
      const u32 x0 = a0[t0], x1 = a0[t1];
      a0[t0] = updh(x0, x1, s0);
      a0[t1] = updh(x1, x0, s1);
      const u32 y0 = a1[t0], y1 = a1[t1];
      a1[t0] = updh(y0, y1, s0);
      a1[t1] = updh(y1, y0, s1);
    }
  } else {
#pragma unroll
    for (int t = 0; t < 16; ++t) {
      const uint4 s = (__builtin_popcount((unsigned)(t & SRm)) & 1) ? cB : cA;
      const u32 q0 = lshuf<PLm>(a0[t ^ PRm], lane, bpa);
      const u32 q1 = lshuf<PLm>(a1[t ^ PRm], lane, bpa);
      a0[t] = updh(a0[t], q0, s);
      a1[t] = updh(a1[t], q1, s);
    }
  }
}

template<int L, int K>
__device__ __forceinline__ void layer2_from(u32 a0[16], u32 a1[16],
                                            const u32* __restrict__ Ush, int lane) {
  if constexpr (K < 10) {
    gate2<L, ORD[L][K]>(a0, a1, Ush, lane);
    layer2_from<L, K + 1>(a0, a1, Ush, lane);
  }
}

// ---------------- embedding with layer-0 fold -> packed state ----------------
__device__ __forceinline__ void build_state(u32 a[16], const float cw[10], const float sw[10],
                                            const u32* __restrict__ Ush, int lane) {
  float u0r[10], u0i[10], u1r[10], u1i[10];
#pragma unroll
  for (int w = 0; w < 10; ++w) {
    const u32* q = &Ush[240 + w * 8];
    const float A = __uint_as_float(q[0]), Br = __uint_as_float(q[1]);
    const float Bi = __uint_as_float(q[2]), Cr = __uint_as_float(q[3]);
    const float Ci = __uint_as_float(q[4]), Dr = __uint_as_float(q[5]);
    const float Di = __uint_as_float(q[6]);
    const float ch = cw[w], sh = sw[w];
    u0r[w] = fmaf(A, ch, Bi * sh);
    u0i[w] = -Br * sh;
    u1r[w] = fmaf(Cr, ch, Di * sh);
    u1i[w] = fmaf(Ci, ch, -Dr * sh);
  }

  float Lr, Li;
  {
    const int b0 = (lane >> 5) & 1;
    Lr = b0 ? u1r[0] : u0r[0];
    Li = b0 ? u1i[0] : u0i[0];
  }
#pragma unroll
  for (int w = 1; w < 6; ++w) {
    const int bb = (lane >> (5 - w)) & 1;
    const float arv = bb ? u1r[w] : u0r[w];
    const float aiv = bb ? u1i[w] : u0i[w];
    const float nr = fmaf(Lr, arv, -Li * aiv);
    const float ni = fmaf(Lr, aiv, Li * arv);
    Lr = nr; Li = ni;
  }

  float t4r[4], t4i[4], lsr[4], lsi[4];
#pragma unroll
  for (int aa = 0; aa < 2; ++aa) {
#pragma unroll
    for (int c2 = 0; c2 < 2; ++c2) {
      const int k = (aa << 1) | c2;
      const float ar6 = aa ? u1r[6] : u0r[6], ai6 = aa ? u1i[6] : u0i[6];
      const float ar7 = c2 ? u1r[7] : u0r[7], ai7 = c2 ? u1i[7] : u0i[7];
      t4r[k] = fmaf(ar6, ar7, -ai6 * ai7);
      t4i[k] = fmaf(ar6, ai7, ai6 * ar7);
      const float ar8 = aa ? u1r[8] : u0r[8], ai8 = aa ? u1i[8] : u0i[8];
      const float ar9 = c2 ? u1r[9] : u0r[9], ai9 = c2 ? u1i[9] : u0i[9];
      const float s4r = fmaf(ar8, ar9, -ai8 * ai9);
      const float s4i = fmaf(ar8, ai9, ai8 * ar9);
      lsr[k] = fmaf(s4r, Lr, -s4i * Li);
      lsi[k] = fmaf(s4r, Li, s4i * Lr);
    }
  }

#pragma unroll
  for (int t = 0; t < 16; ++t) {
    const int hi4 = t >> 2, lo4 = t & 3;
    const float re = fmaf(t4r[hi4], lsr[lo4], -t4i[hi4] * lsi[lo4]);
    const float im = fmaf(t4r[hi4], lsi[lo4],  t4i[hi4] * lsr[lo4]);
    a[t] = pk2(re, im);
  }
}

// ---------------- main kernel: one wave per TWO samples ----------------
template<bool FROMWS>
__global__ __launch_bounds__(256, 4) void qnn_kernel(
    const float* __restrict__ x, const float* __restrict__ Wpre,
    const float* __restrict__ bpre, const float* __restrict__ qw,
    const float* __restrict__ Wpost, const float* __restrict__ bpost,
    const u32* __restrict__ ws, float* __restrict__ out)
{
  __shared__ __align__(16) u32 Ush[320];
  __shared__ __align__(16) float gtab[16 * 64];

  const int tid = threadIdx.x;
  if constexpr (FROMWS) {
    if (tid < 80) ((uint4*)Ush)[tid] = ((const uint4*)ws)[tid];
    ((float4*)gtab)[tid] = ((const float4*)(ws + 320))[tid];
  } else {
    if (tid < 40) compute_gate_words(tid, qw, Ush);
#pragma unroll
    for (int k = 0; k < 4; ++k) {
      const int idx = tid * 4 + k;
      gtab[idx] = compute_gtab_entry(idx, Wpost);
    }
  }
  __syncthreads();

  const int lane = tid & 63;
  const int wid = tid >> 6;
  const int half = lane >> 5;
  const int hl5 = lane & 31;
  const int b0 = blockIdx.x * 8 + wid * 2;

  // ---- pre-net, half-wave: lanes 0-31 -> b0, lanes 32-63 -> b1 ----
  const float* xr = x + (size_t)(b0 + half) * 128;
  float xv[4];
#pragma unroll
  for (int k = 0; k < 4; ++k) xv[k] = xr[hl5 + 32 * k];

  float cw0[10], sw0[10], cw1[10], sw1[10];
#pragma unroll
  for (int w = 0; w < 10; ++w) {
    float p = 0.f;
#pragma unroll
    for (int k = 0; k < 4; ++k)
      p = fmaf(xv[k], Wpre[w * 128 + hl5 + 32 * k], p);
    p = half_sum(p);
    const float e = __expf(2.f * (p + bpre[w]));
    const float ang = 1.f - 2.f * __builtin_amdgcn_rcpf(e + 1.f);
    const float h = 0.5f * ang;
    const float c_own = __cosf(h);
    const float s_own = __sinf(h);
    const float c_oth = xswapf(c_own, lane);
    const float s_oth = xswapf(s_own, lane);
    cw0[w] = half ? c_oth : c_own;
    sw0[w] = half ? s_oth : s_own;
    cw1[w] = half ? c_own : c_oth;
    sw1[w] = half ? s_own : s_oth;
  }

  // ---- build both states (embedding + layer-0 fold) ----
  u32 a0[16], a1[16];
  build_state(a0, cw0, sw0, Ush, lane);
  build_state(a1, cw1, sw1, Ush, lane);

  // ---- layers 1..3, both samples, shared gate overhead ----
  layer2_from<1, 0>(a0, a1, Ush, lane);
  layer2_from<2, 0>(a0, a1, Ush, lane);
  layer2_from<3, 0>(a0, a1, Ush, lane);

  // ---- epilogue ----
  float acc0 = 0.f, acc1 = 0.f;
#pragma unroll
  for (int t = 0; t < 16; ++t) {
    const float g = gtab[t * 64 + lane];
#if HAS_FDOT2
    typedef _Float16 h2 __attribute__((ext_vector_type(2)));
    const h2 ah0 = __builtin_bit_cast(h2, a0[t]);
    const h2 ah1 = __builtin_bit_cast(h2, a1[t]);
    acc0 = fmaf(__builtin_amdgcn_fdot2(ah0, ah0, 0.f, false), g, acc0);
    acc1 = fmaf(__builtin_amdgcn_fdot2(ah1, ah1, 0.f, false), g, acc1);
#else
    union H2U { u32 u; _Float16 h[2]; } z0, z1;
    z0.u = a0[t]; z1.u = a1[t];
    const float r0 = (float)z0.h[0], i0 = (float)z0.h[1];
    const float r1 = (float)z1.h[0], i1 = (float)z1.h[1];
    acc0 = fmaf(fmaf(r0, r0, i0 * i0), g, acc0);
    acc1 = fmaf(fmaf(r1, r1, i1 * i1), g, acc1);
#endif
  }
  acc0 = wave_sum(acc0, lane);
  acc1 = wave_sum(acc1, lane);

  if (lane == 0) {
    const float bp = bpost[0];
    out[b0]     = __builtin_amdgcn_rcpf(1.f + __expf(-(acc0 + bp)));
    out[b0 + 1] = __builtin_amdgcn_rcpf(1.f + __expf(-(acc1 + bp)));
  }
}

extern "C" void kernel_launch(void* const* d_in, const int* in_sizes, int n_in,
                              void* d_out, int out_size, void* d_ws, size_t ws_size,
                              hipStream_t stream) {
  const float* x     = (const float*)d_in[0];
  const float* Wpre  = (const float*)d_in[1];
  const float* bpre  = (const float*)d_in[2];
  const float* qw    = (const float*)d_in[3];
  const float* Wpost = (const float*)d_in[4];
  const float* bpost = (const float*)d_in[5];
  float* out = (float*)d_out;
  u32* ws = (u32*)d_ws;

  (void)in_sizes; (void)n_in; (void)out_size;

  if (ws_size >= WS_WORDS * sizeof(u32)) {
    qnn_setup<<<1, 64, 0, stream>>>(qw, Wpost, ws);
    qnn_kernel<true><<<BATCH / 8, 256, 0, stream>>>(x, Wpre, bpre, qw, Wpost, bpost, ws, out);
  } else {
    qnn_kernel<false><<<BATCH / 8, 256, 0, stream>>>(x, Wpre, bpre, qw, Wpost, bpost, ws, out);
  }
}

// Round 16
// 153.391 us; speedup vs baseline: 1.1493x; 1.0125x over previous
//
#include <hip/hip_runtime.h>
#include <math.h>

#define BATCH 32768

typedef unsigned int u32;

#if defined(__has_builtin)
#if __has_builtin(__builtin_amdgcn_permlane32_swap) && __has_builtin(__builtin_amdgcn_permlane16_swap)
#define USE_PERMLANE 1
#else
#define USE_PERMLANE 0
#endif
#if __has_builtin(__builtin_amdgcn_fdot2)
#define HAS_FDOT2 1
#else
#define HAS_FDOT2 0
#endif
#else
#define USE_PERMLANE 0
#define HAS_FDOT2 0
#endif

// ---------------------------------------------------------------------------
// Compile-time circuit derivation (lazy CNOT tracking over GF(2)).
// Physical index p (10 bits): lane = p>>4 (bits 9..4), reg t = p&15.
// One amp = one u32 = packed fp16 {re(lo), im(hi)}.
// Layer 0 folded into the embedding; layers 1..3 are generalized pair-mix
// gates. Each wave simulates TWO samples (a0/a1) sharing gate overhead.
// Cross-lane policy (rounds 9-13 ledger): VALU ops cost ~2cyc at the margin,
// DS ops are ~free -> ALL gate partner fetches via ds_swizzle/ds_bpermute.
// Round 16: block-startup cost (r15 measured 6.4us/dispatch) reduced by
// parallelizing the 40-gate trig: 160 threads each compute ONE cos+sin pair
// (serial libm depth 8x -> 2x), then 40 threads combine with multiplies.
// gtab build uses stride-256 indexing (same values, conflict-free writes).
// ---------------------------------------------------------------------------
struct GateC { unsigned prt, sel; };
struct CircuitT { GateC g[4][10]; unsigned srow[10]; };

constexpr CircuitT make_circuit() {
  CircuitT C{};
  unsigned row[10], col[10];
  for (int b = 0; b < 10; ++b) { row[b] = 1u << b; col[b] = 1u << b; }
  for (int l = 0; l < 4; ++l) {
    for (int w = 0; w < 10; ++w) {
      C.g[l][w].prt = col[9 - w];
      C.g[l][w].sel = row[9 - w];
    }
    const int r = (l % 9) + 1;
    for (int w = 0; w < 10; ++w) {
      const int c = w, t = (w + r) % 10;
      const int bc = 9 - c, bt = 9 - t;
      row[bt] ^= row[bc];
      col[bc] ^= col[bt];
    }
  }
  for (int i = 0; i < 10; ++i) C.srow[i] = row[9 - i];
  return C;
}
constexpr CircuitT CIRC = make_circuit();

// Within-layer gate order (commuting gates; interleave DS bursts with REG work).
constexpr int ORD[4][10] = {
  {0,1,2,3,4,5,6,7,8,9},
  {0,6,1,7,2,8,3,4,9,5},
  {0,2,1,3,7,4,8,5,9,6},
  {0,3,1,2,4,5,6,7,8,9},
};

// ---------------- cross-lane: all-DS for gate partner fetch ----------------
template<int M>
__device__ __forceinline__ u32 lshuf(u32 v, int lane, int bpa) {
  static_assert(M != 0, "mask must be nonzero");
  if constexpr ((M & 32) != 0) {
    return (u32)__builtin_amdgcn_ds_bpermute(bpa, (int)v);
  } else {
    return (u32)__builtin_amdgcn_ds_swizzle((int)v, 0x1F | (M << 10));
  }
}

// ---------------- float cross-lane (prenet/epilogue reductions) ----------------
template<int CTRL>
__device__ __forceinline__ float dppf(float v) {
  const int i = __float_as_int(v);
  return __int_as_float(__builtin_amdgcn_update_dpp(i, i, CTRL, 0xF, 0xF, false));
}
__device__ __forceinline__ float shflx(float v, int m) { return __shfl_xor(v, m, 64); }

__device__ __forceinline__ float wave_sum(float v, int lane) {
  v += dppf<0xB1>(v);
  v += dppf<0x4E>(v);
  v += dppf<0x141>(v);
  v += dppf<0x140>(v);
#if USE_PERMLANE
  { auto r = __builtin_amdgcn_permlane16_swap(__float_as_uint(v), __float_as_uint(v), false, false);
    v = __uint_as_float(r[0]) + __uint_as_float(r[1]); }
  { auto r = __builtin_amdgcn_permlane32_swap(__float_as_uint(v), __float_as_uint(v), false, false);
    v = __uint_as_float(r[0]) + __uint_as_float(r[1]); }
#else
  v += shflx(v, 16);
  v += shflx(v, 32);
#endif
  return v;
}

__device__ __forceinline__ float half_sum(float v) {
  v += dppf<0xB1>(v);
  v += dppf<0x4E>(v);
  v += dppf<0x141>(v);
  v += dppf<0x140>(v);
#if USE_PERMLANE
  { auto r = __builtin_amdgcn_permlane16_swap(__float_as_uint(v), __float_as_uint(v), false, false);
    v = __uint_as_float(r[0]) + __uint_as_float(r[1]); }
#else
  v += shflx(v, 16);
#endif
  return v;
}

__device__ __forceinline__ float xswapf(float v, int lane) {
#if USE_PERMLANE
  auto r = __builtin_amdgcn_permlane32_swap(__float_as_uint(v), __float_as_uint(v), false, false);
  return (lane & 32) ? __uint_as_float(r[0]) : __uint_as_float(r[1]);
#else
  return shflx(v, 32);
#endif
}

// ---------------- packed fp16 primitives ----------------
__device__ __forceinline__ u32 pk_mul_h(u32 a, u32 b) {
  u32 d; asm("v_pk_mul_f16 %0, %1, %2" : "=v"(d) : "v"(a), "v"(b)); return d;
}
__device__ __forceinline__ u32 pk_fma_h(u32 a, u32 b, u32 c) {
  u32 d; asm("v_pk_fma_f16 %0, %1, %2, %3" : "=v"(d) : "v"(a), "v"(b), "v"(c)); return d;
}
__device__ __forceinline__ u32 pk_fma_hsw(u32 a, u32 b, u32 c) {
  u32 d;
  asm("v_pk_fma_f16 %0, %1, %2, %3 op_sel:[1,0,0] op_sel_hi:[0,1,1]"
      : "=v"(d) : "v"(a), "v"(b), "v"(c));
  return d;
}
__device__ __forceinline__ u32 pk2(float lo, float hi) {
  auto h = __builtin_amdgcn_cvt_pkrtz(lo, hi);
  return __builtin_bit_cast(u32, h);
}
__device__ __forceinline__ u32 updh(u32 a, u32 q, const uint4 s) {
  u32 t = pk_mul_h(a, s.x);
  t = pk_fma_hsw(a, s.y, t);
  t = pk_fma_h(q, s.z, t);
  t = pk_fma_hsw(q, s.w, t);
  return t;
}

__device__ __forceinline__ float compute_gtab_entry(int idx, const float* __restrict__ Wpost) {
  const int t = idx >> 6;
  const int l6 = idx & 63;
  float g = 0.f;
#pragma unroll
  for (int i = 0; i < 10; ++i) {
    const int sl = (int)(CIRC.srow[i] >> 4);
    const int sr = (int)(CIRC.srow[i] & 15u);
    const int par = (__popc(l6 & sl) + __popc(t & sr)) & 1;
    const float wv = Wpost[i];
    g += par ? -wv : wv;
  }
  return g;
}

// ---------------- gate on two states (shared overhead) ----------------
template<int L, int W>
__device__ __forceinline__ void gate2(u32 a0[16], u32 a1[16],
                                      const u32* __restrict__ Ush, int lane) {
  constexpr unsigned PRT = CIRC.g[L][W].prt;
  constexpr unsigned SEL = CIRC.g[L][W].sel;
  constexpr int PLm = (int)(PRT >> 4), PRm = (int)(PRT & 15u);
  constexpr int SLm = (int)(SEL >> 4), SRm = (int)(SEL & 15u);

  int hl = 0;
  if constexpr (SLm != 0) hl = __popc(lane & SLm) & 1;

  const u32* gb = Ush + (L * 10 + W - 10) * 8;
  const uint4 cA = *(const uint4*)(gb + (hl << 2));
  uint4 cB;
  if constexpr (SRm != 0) cB = *(const uint4*)(gb + ((hl ^ 1) << 2));
  else                    cB = cA;

  int bpa = 0;
  if constexpr ((PLm & 32) != 0) bpa = (lane ^ PLm) << 2;

  if constexpr (PLm == 0) {
    constexpr int LB = PRm & (-PRm);
#pragma unroll
    for (int t0 = 0; t0 < 16; ++t0) {
      if (t0 & LB) continue;
      const int t1 = t0 ^ PRm;
      const uint4 s0 = (__builtin_popcount((unsigned)(t0 & SRm)) & 1) ? cB : cA;
      const uint4 s1 = (__builtin_popcount((unsigned)(t1 & SRm)) & 1) ? cB : cA;
      const u32 x0 = a0[t0], x1 = a0[t1];
      a0[t0] = updh(x0, x1, s0);
      a0[t1] = updh(x1, x0, s1);
      const u32 y0 = a1[t0], y1 = a1[t1];
      a1[t0] = updh(y0, y1, s0);
      a1[t1] = updh(y1, y0, s1);
    }
  } else {
#pragma unroll
    for (int t = 0; t < 16; ++t) {
      const uint4 s = (__builtin_popcount((unsigned)(t & SRm)) & 1) ? cB : cA;
      const u32 q0 = lshuf<PLm>(a0[t ^ PRm], lane, bpa);
      const u32 q1 = lshuf<PLm>(a1[t ^ PRm], lane, bpa);
      a0[t] = updh(a0[t], q0, s);
      a1[t] = updh(a1[t], q1, s);
    }
  }
}

template<int L, int K>
__device__ __forceinline__ void layer2_from(u32 a0[16], u32 a1[16],
                                            const u32* __restrict__ Ush, int lane) {
  if constexpr (K < 10) {
    gate2<L, ORD[L][K]>(a0, a1, Ush, lane);
    layer2_from<L, K + 1>(a0, a1, Ush, lane);
  }
}

// ---------------- embedding with layer-0 fold -> packed state ----------------
__device__ __forceinline__ void build_state(u32 a[16], const float cw[10], const float sw[10],
                                            const u32* __restrict__ Ush, int lane) {
  float u0r[10], u0i[10], u1r[10], u1i[10];
#pragma unroll
  for (int w = 0; w < 10; ++w) {
    const u32* q = &Ush[240 + w * 8];
    const float A = __uint_as_float(q[0]), Br = __uint_as_float(q[1]);
    const float Bi = __uint_as_float(q[2]), Cr = __uint_as_float(q[3]);
    const float Ci = __uint_as_float(q[4]), Dr = __uint_as_float(q[5]);
    const float Di = __uint_as_float(q[6]);
    const float ch = cw[w], sh = sw[w];
    u0r[w] = fmaf(A, ch, Bi * sh);
    u0i[w] = -Br * sh;
    u1r[w] = fmaf(Cr, ch, Di * sh);
    u1i[w] = fmaf(Ci, ch, -Dr * sh);
  }

  float Lr, Li;
  {
    const int b0 = (lane >> 5) & 1;
    Lr = b0 ? u1r[0] : u0r[0];
    Li = b0 ? u1i[0] : u0i[0];
  }
#pragma unroll
  for (int w = 1; w < 6; ++w) {
    const int bb = (lane >> (5 - w)) & 1;
    const float arv = bb ? u1r[w] : u0r[w];
    const float aiv = bb ? u1i[w] : u0i[w];
    const float nr = fmaf(Lr, arv, -Li * aiv);
    const float ni = fmaf(Lr, aiv, Li * arv);
    Lr = nr; Li = ni;
  }

  float t4r[4], t4i[4], lsr[4], lsi[4];
#pragma unroll
  for (int aa = 0; aa < 2; ++aa) {
#pragma unroll
    for (int c2 = 0; c2 < 2; ++c2) {
      const int k = (aa << 1) | c2;
      const float ar6 = aa ? u1r[6] : u0r[6], ai6 = aa ? u1i[6] : u0i[6];
      const float ar7 = c2 ? u1r[7] : u0r[7], ai7 = c2 ? u1i[7] : u0i[7];
      t4r[k] = fmaf(ar6, ar7, -ai6 * ai7);
      t4i[k] = fmaf(ar6, ai7, ai6 * ar7);
      const float ar8 = aa ? u1r[8] : u0r[8], ai8 = aa ? u1i[8] : u0i[8];
      const float ar9 = c2 ? u1r[9] : u0r[9], ai9 = c2 ? u1i[9] : u0i[9];
      const float s4r = fmaf(ar8, ar9, -ai8 * ai9);
      const float s4i = fmaf(ar8, ai9, ai8 * ar9);
      lsr[k] = fmaf(s4r, Lr, -s4i * Li);
      lsi[k] = fmaf(s4r, Li, s4i * Lr);
    }
  }

#pragma unroll
  for (int t = 0; t < 16; ++t) {
    const int hi4 = t >> 2, lo4 = t & 3;
    const float re = fmaf(t4r[hi4], lsr[lo4], -t4i[hi4] * lsi[lo4]);
    const float im = fmaf(t4r[hi4], lsi[lo4],  t4i[hi4] * lsr[lo4]);
    a[t] = pk2(re, im);
  }
}

// ---------------- main kernel: one wave per TWO samples ----------------
__global__ __launch_bounds__(256, 4) void qnn_kernel(
    const float* __restrict__ x, const float* __restrict__ Wpre,
    const float* __restrict__ bpre, const float* __restrict__ qw,
    const float* __restrict__ Wpost, const float* __restrict__ bpost,
    float* __restrict__ out)
{
  __shared__ __align__(16) u32 Ush[320];
  __shared__ __align__(16) float gtab[16 * 64];
  __shared__ float trig[160][2];   // [gate*4 + angle]{cos,sin}

  const int tid = threadIdx.x;

  // Stage 1: 160 threads each compute ONE cos+sin pair (libm depth 2, not 8).
  if (tid < 160) {
    const int g = tid >> 2, a = tid & 3;
    const float phi = qw[g * 3 + 0];
    const float th  = qw[g * 3 + 1];
    const float om  = qw[g * 3 + 2];
    float ang;
    if (a == 0)      ang = 0.5f * th;
    else if (a == 1) ang = phi;
    else if (a == 2) ang = om;
    else             ang = phi + om;
    trig[tid][0] = cosf(ang);
    trig[tid][1] = sinf(ang);
  }
  // gtab build: stride-256 indexing -> conflict-free writes (same values).
#pragma unroll
  for (int k = 0; k < 4; ++k) {
    const int idx = k * 256 + tid;
    gtab[idx] = compute_gtab_entry(idx, Wpost);
  }
  __syncthreads();

  // Stage 2: combine trig into gate coefficient words (bitwise-identical
  // expressions to the original compute: Br = -cos(phi)*s_, etc.)
  if (tid < 40) {
    const float c   = trig[tid * 4 + 0][0], s_  = trig[tid * 4 + 0][1];
    const float cph = trig[tid * 4 + 1][0], sph = trig[tid * 4 + 1][1];
    const float com = trig[tid * 4 + 2][0], som = trig[tid * 4 + 2][1];
    const float cpo = trig[tid * 4 + 3][0], spo = trig[tid * 4 + 3][1];
    const float A  = c;
    const float Br = -cph * s_, Bi = -sph * s_;
    const float Cr =  com * s_, Ci =  som * s_;
    const float Dr =  cpo * c,  Di =  spo * c;
    if (tid < 10) {
      u32* q = &Ush[240 + tid * 8];
      q[0] = __float_as_uint(A);  q[1] = __float_as_uint(Br);
      q[2] = __float_as_uint(Bi); q[3] = __float_as_uint(Cr);
      q[4] = __float_as_uint(Ci); q[5] = __float_as_uint(Dr);
      q[6] = __float_as_uint(Di); q[7] = 0u;
    } else {
      u32* p = &Ush[(tid - 10) * 8];
      p[0] = pk2(A, A);   p[1] = pk2(0.f, 0.f);
      p[2] = pk2(Br, Br); p[3] = pk2(-Bi, Bi);
      p[4] = pk2(Dr, Dr); p[5] = pk2(-Di, Di);
      p[6] = pk2(Cr, Cr); p[7] = pk2(-Ci, Ci);
    }
  }
  __syncthreads();

  const int lane = tid & 63;
  const int wid = tid >> 6;
  const int half = lane >> 5;
  const int hl5 = lane & 31;
  const int b0 = blockIdx.x * 8 + wid * 2;

  // ---- pre-net, half-wave: lanes 0-31 -> b0, lanes 32-63 -> b1 ----
  const float* xr = x + (size_t)(b0 + half) * 128;
  float xv[4];
#pragma unroll
  for (int k = 0; k < 4; ++k) xv[k] = xr[hl5 + 32 * k];

  float cw0[10], sw0[10], cw1[10], sw1[10];
#pragma unroll
  for (int w = 0; w < 10; ++w) {
    float p = 0.f;
#pragma unroll
    for (int k = 0; k < 4; ++k)
      p = fmaf(xv[k], Wpre[w * 128 + hl5 + 32 * k], p);
    p = half_sum(p);
    const float e = __expf(2.f * (p + bpre[w]));
    const float ang = 1.f - 2.f * __builtin_amdgcn_rcpf(e + 1.f);
    const float h = 0.5f * ang;
    const float c_own = __cosf(h);
    const float s_own = __sinf(h);
    const float c_oth = xswapf(c_own, lane);
    const float s_oth = xswapf(s_own, lane);
    cw0[w] = half ? c_oth : c_own;
    sw0[w] = half ? s_oth : s_own;
    cw1[w] = half ? c_own : c_oth;
    sw1[w] = half ? s_own : s_oth;
  }

  // ---- build both states (embedding + layer-0 fold) ----
  u32 a0[16], a1[16];
  build_state(a0, cw0, sw0, Ush, lane);
  build_state(a1, cw1, sw1, Ush, lane);

  // ---- layers 1..3, both samples, shared gate overhead ----
  layer2_from<1, 0>(a0, a1, Ush, lane);
  layer2_from<2, 0>(a0, a1, Ush, lane);
  layer2_from<3, 0>(a0, a1, Ush, lane);

  // ---- epilogue ----
  float acc0 = 0.f, acc1 = 0.f;
#pragma unroll
  for (int t = 0; t < 16; ++t) {
    const float g = gtab[t * 64 + lane];
#if HAS_FDOT2
    typedef _Float16 h2 __attribute__((ext_vector_type(2)));
    const h2 ah0 = __builtin_bit_cast(h2, a0[t]);
    const h2 ah1 = __builtin_bit_cast(h2, a1[t]);
    acc0 = fmaf(__builtin_amdgcn_fdot2(ah0, ah0, 0.f, false), g, acc0);
    acc1 = fmaf(__builtin_amdgcn_fdot2(ah1, ah1, 0.f, false), g, acc1);
#else
    union H2U { u32 u; _Float16 h[2]; } z0, z1;
    z0.u = a0[t]; z1.u = a1[t];
    const float r0 = (float)z0.h[0], i0 = (float)z0.h[1];
    const float r1 = (float)z1.h[0], i1 = (float)z1.h[1];
    acc0 = fmaf(fmaf(r0, r0, i0 * i0), g, acc0);
    acc1 = fmaf(fmaf(r1, r1, i1 * i1), g, acc1);
#endif
  }
  acc0 = wave_sum(acc0, lane);
  acc1 = wave_sum(acc1, lane);

  if (lane == 0) {
    const float bp = bpost[0];
    out[b0]     = __builtin_amdgcn_rcpf(1.f + __expf(-(acc0 + bp)));
    out[b0 + 1] = __builtin_amdgcn_rcpf(1.f + __expf(-(acc1 + bp)));
  }
}

extern "C" void kernel_launch(void* const* d_in, const int* in_sizes, int n_in,
                              void* d_out, int out_size, void* d_ws, size_t ws_size,
                              hipStream_t stream) {
  const float* x     = (const float*)d_in[0];
  const float* Wpre  = (const float*)d_in[1];
  const float* bpre  = (const float*)d_in[2];
  const float* qw    = (const float*)d_in[3];
  const float* Wpost = (const float*)d_in[4];
  const float* bpost = (const float*)d_in[5];
  float* out = (float*)d_out;

  (void)in_sizes; (void)n_in; (void)out_size; (void)d_ws; (void)ws_size;

  qnn_kernel<<<BATCH / 8, 256, 0, stream>>>(x, Wpre, bpre, qw, Wpost, bpost, out);
}